// Round 3
// baseline (997.750 us; speedup 1.0000x reference)
//
#include <hip/hip_runtime.h>

#define NB 4096
#define NT 512
#define NI 25
#define NH 20
#define NL 10

#if __has_builtin(__builtin_amdgcn_rcpf)
__device__ __forceinline__ float rcpf(float x){ return __builtin_amdgcn_rcpf(x); }
#else
__device__ __forceinline__ float rcpf(float x){ return 1.0f/x; }
#endif

struct Smem {
  float xbuf[4][28];
  float hbuf[4][20];
  float gbuf[4][80];
  float zbuf[4][12];
};

__device__ __forceinline__ void load_wb(const float* __restrict__ Wih, const float* __restrict__ Whh,
                                        const float* __restrict__ bih, const float* __restrict__ bhh,
                                        int k, float (&wih)[5][25], float (&whh)[5][20], float (&bias)[5])
{
#pragma unroll
  for (int g=0; g<5; ++g){
    const int G = 5*k+g;
#pragma unroll
    for (int i=0;i<25;++i) wih[g][i] = Wih[G*25+i];
#pragma unroll
    for (int j=0;j<20;++j) whh[g][j] = Whh[G*20+j];
    bias[g] = bih[G] + bhh[G];
  }
}

template<bool DEC>
__device__ __forceinline__ void lstm_phase(
    const float* __restrict__ xrowbase,  // x + (size_t)b*NT*NI
    Smem* sm, int r, int k,
    const float (&wih)[5][25], const float (&whh)[5][20], const float (&bias)[5],
    float (&c)[2],
    const float (&ow)[2][20], const float (&obias)[2],
    float* __restrict__ xhat_out)        // out + (size_t)b*NT*NI when DEC
{
  const bool is_g = ((k>>2)==2);
  const float gmul = is_g ? -2.0f : -1.0f;
  // prefetch t=0
  float u0 = xrowbase[k];
  float u1 = (k<9) ? xrowbase[16+k] : 0.0f;
  for (int t=0; t<NT; ++t){
    // stage x for step t
    sm->xbuf[r][k] = u0;
    if (k<9) sm->xbuf[r][16+k] = u1;
    // issue prefetch for t+1
    if (t+1 < NT){
      const float* xr = xrowbase + (size_t)(t+1)*NI;
      u0 = xr[k];
      if (k<9) u1 = xr[16+k];
    }
    __syncthreads();
    float xreg[25], hreg[20];
#pragma unroll
    for (int i=0;i<25;++i) xreg[i] = sm->xbuf[r][i];
#pragma unroll
    for (int j=0;j<20;++j) hreg[j] = sm->hbuf[r][j];

    if (DEC && t>0 && k<13){
      // output projection for step t-1 (hreg == h after update of t-1)
      float a0 = obias[0];
#pragma unroll
      for (int j=0;j<20;++j) a0 = fmaf(ow[0][j], hreg[j], a0);
      xhat_out[(size_t)(t-1)*NI + k] = a0;
      if (k<12){
        float a1 = obias[1];
#pragma unroll
        for (int j=0;j<20;++j) a1 = fmaf(ow[1][j], hreg[j], a1);
        xhat_out[(size_t)(t-1)*NI + 13 + k] = a1;
      }
    }

    float acc[5];
#pragma unroll
    for (int g=0; g<5; ++g) acc[g]=bias[g];
#pragma unroll
    for (int i=0;i<25;++i){
      const float xv = xreg[i];
#pragma unroll
      for (int g=0;g<5;++g) acc[g] = fmaf(wih[g][i], xv, acc[g]);
    }
#pragma unroll
    for (int j=0;j<20;++j){
      const float hv = hreg[j];
#pragma unroll
      for (int g=0;g<5;++g) acc[g] = fmaf(whh[g][j], hv, acc[g]);
    }
    // activation: sigmoid for i,f,o ; tanh via 2*sigmoid(2x)-1 for g (NaN-safe)
#pragma unroll
    for (int g=0; g<5; ++g){
      float e = __expf(gmul*acc[g]);
      float s = rcpf(1.0f + e);
      float res = is_g ? (2.0f*s - 1.0f) : s;
      sm->gbuf[r][5*k+g] = res;
    }
    __syncthreads();
    {
      float ii = sm->gbuf[r][k], ff = sm->gbuf[r][k+20], gg = sm->gbuf[r][k+40], oo = sm->gbuf[r][k+60];
      float cn = fmaf(ff, c[0], ii*gg);
      c[0] = cn;
      float e = __expf(-2.0f*cn);
      float th = 2.0f*rcpf(1.0f + e) - 1.0f;   // tanh, saturates safely
      sm->hbuf[r][k] = oo*th;
      if (k<4){
        float i2 = sm->gbuf[r][16+k], f2_ = sm->gbuf[r][36+k], g2 = sm->gbuf[r][56+k], o2 = sm->gbuf[r][76+k];
        float cn2 = fmaf(f2_, c[1], i2*g2);
        c[1] = cn2;
        float e2 = __expf(-2.0f*cn2);
        float th2 = 2.0f*rcpf(1.0f + e2) - 1.0f;
        sm->hbuf[r][16+k] = o2*th2;
      }
    }
    // next-iteration __syncthreads orders hbuf writes vs reads
  }
}

__global__ __launch_bounds__(64,1) void lstm_vae_kernel(
  const float* __restrict__ x, const float* __restrict__ h0, const float* __restrict__ c0,
  const float* __restrict__ noise,
  const float* __restrict__ eWih, const float* __restrict__ eWhh, const float* __restrict__ ebih, const float* __restrict__ ebhh,
  const float* __restrict__ dWih, const float* __restrict__ dWhh, const float* __restrict__ dbih, const float* __restrict__ dbhh,
  const float* __restrict__ mW, const float* __restrict__ mb,
  const float* __restrict__ lW, const float* __restrict__ lb,
  const float* __restrict__ iW, const float* __restrict__ ib,
  const float* __restrict__ oW, const float* __restrict__ ob,
  float* __restrict__ out)
{
  __shared__ Smem sm;
  const int lane = threadIdx.x;
  const int r = lane>>4, k = lane&15;
  const int b = blockIdx.x*4 + r;
  const float* xrow = x + (size_t)b*NT*NI;

  float wih[5][25], whh[5][20], bias[5];
  float ow[2][20], obias[2];
  float c[2] = {0.f, 0.f};

  // init encoder state from h0/c0 ([1,B,H])
  sm.hbuf[r][k] = h0[(size_t)b*NH + k];
  c[0] = c0[(size_t)b*NH + k];
  if (k<4){
    sm.hbuf[r][16+k] = h0[(size_t)b*NH + 16+k];
    c[1] = c0[(size_t)b*NH + 16+k];
  }

  load_wb(eWih, eWhh, ebih, ebhh, k, wih, whh, bias);
  lstm_phase<false>(xrow, &sm, r, k, wih, whh, bias, c, ow, obias, nullptr);

  __syncthreads();
  float hT[20];
#pragma unroll
  for (int j=0;j<20;++j) hT[j] = sm.hbuf[r][j];

  const size_t OFF1 = (size_t)NB*NT*NI;            // mean
  const size_t OFF2 = OFF1 + (size_t)NB*NL;        // logvar
  const size_t OFF3 = OFF2 + (size_t)NB*NL;        // z
  const size_t OFF4 = OFF3 + (size_t)NB*NL;        // h_n
  const size_t OFF5 = OFF4 + (size_t)NB*NH;        // c_n

  out[OFF4 + (size_t)b*NH + k] = hT[k];
  out[OFF5 + (size_t)b*NH + k] = c[0];
  if (k<4){
    out[OFF4 + (size_t)b*NH + 16+k] = hT[16+k];
    out[OFF5 + (size_t)b*NH + 16+k] = c[1];
  }

  if (k<10){
    float m = mb[k], lv = lb[k];
#pragma unroll
    for (int j=0;j<20;++j){
      m  = fmaf(mW[k*20+j], hT[j], m);
      lv = fmaf(lW[k*20+j], hT[j], lv);
    }
    float sd = __expf(0.5f*lv);
    float zz = fmaf(noise[(size_t)b*NL + k], sd, m);
    out[OFF1 + (size_t)b*NL + k] = m;
    out[OFF2 + (size_t)b*NL + k] = lv;
    out[OFF3 + (size_t)b*NL + k] = zz;
    sm.zbuf[r][k] = zz;
  }
  __syncthreads();
  {
    float hd = ib[k];
#pragma unroll
    for (int l=0;l<10;++l) hd = fmaf(iW[k*10+l], sm.zbuf[r][l], hd);
    sm.hbuf[r][k] = hd; c[0] = hd;
    if (k<4){
      float hd2 = ib[16+k];
#pragma unroll
      for (int l=0;l<10;++l) hd2 = fmaf(iW[(16+k)*10+l], sm.zbuf[r][l], hd2);
      sm.hbuf[r][16+k] = hd2; c[1] = hd2;
    }
  }

  load_wb(dWih, dWhh, dbih, dbhh, k, wih, whh, bias);
  if (k<13){
#pragma unroll
    for (int j=0;j<20;++j) ow[0][j] = oW[k*20+j];
    obias[0] = ob[k];
    if (k<12){
#pragma unroll
      for (int j=0;j<20;++j) ow[1][j] = oW[(13+k)*20+j];
      obias[1] = ob[13+k];
    }
  }
  float* xhat = out + (size_t)b*NT*NI;
  lstm_phase<true>(xrow, &sm, r, k, wih, whh, bias, c, ow, obias, xhat);

  // final output projection for t = NT-1
  __syncthreads();
#pragma unroll
  for (int j=0;j<20;++j) hT[j] = sm.hbuf[r][j];
  if (k<13){
    float a0 = obias[0];
#pragma unroll
    for (int j=0;j<20;++j) a0 = fmaf(ow[0][j], hT[j], a0);
    xhat[(size_t)(NT-1)*NI + k] = a0;
    if (k<12){
      float a1 = obias[1];
#pragma unroll
      for (int j=0;j<20;++j) a1 = fmaf(ow[1][j], hT[j], a1);
      xhat[(size_t)(NT-1)*NI + 13+k] = a1;
    }
  }
}

extern "C" void kernel_launch(void* const* d_in, const int* in_sizes, int n_in,
                              void* d_out, int out_size, void* d_ws, size_t ws_size,
                              hipStream_t stream) {
  const float* x     = (const float*)d_in[0];
  const float* h0    = (const float*)d_in[1];
  const float* c0    = (const float*)d_in[2];
  const float* noise = (const float*)d_in[3];
  const float* eWih  = (const float*)d_in[4];
  const float* eWhh  = (const float*)d_in[5];
  const float* ebih  = (const float*)d_in[6];
  const float* ebhh  = (const float*)d_in[7];
  const float* dWih  = (const float*)d_in[8];
  const float* dWhh  = (const float*)d_in[9];
  const float* dbih  = (const float*)d_in[10];
  const float* dbhh  = (const float*)d_in[11];
  const float* mW    = (const float*)d_in[12];
  const float* mb    = (const float*)d_in[13];
  const float* lW    = (const float*)d_in[14];
  const float* lb    = (const float*)d_in[15];
  const float* iW    = (const float*)d_in[16];
  const float* ib    = (const float*)d_in[17];
  const float* oW    = (const float*)d_in[18];
  const float* ob    = (const float*)d_in[19];
  float* out = (float*)d_out;

  hipLaunchKernelGGL(lstm_vae_kernel, dim3(NB/4), dim3(64), 0, stream,
                     x, h0, c0, noise,
                     eWih, eWhh, ebih, ebhh,
                     dWih, dWhh, dbih, dbhh,
                     mW, mb, lW, lb, iW, ib, oW, ob, out);
}